// Round 9
// baseline (463.132 us; speedup 1.0000x reference)
//
#include <hip/hip_runtime.h>
#include <hip/hip_bf16.h>
#include <stdint.h>

typedef __attribute__((ext_vector_type(4))) float f32x4;
typedef __attribute__((ext_vector_type(8))) short s16x8;
typedef __attribute__((ext_vector_type(4))) unsigned short u16x4;
typedef unsigned short u16;

#define NB 16
#define NM 2048
#define ND 768
#define NH 12
#define NROWS (NB*NM)
// 0.125 * log2(e)
#define QSCALE 0.18033688011112042f

__device__ __forceinline__ u16 bf16rn(float v) {
  union { float f; uint32_t u; } x; x.f = v;
  uint32_t r = x.u + 0x7FFFu + ((x.u >> 16) & 1u);
  return (u16)(r >> 16);
}

__device__ __forceinline__ f32x4 mfma16(s16x8 a, s16x8 b, f32x4 c) {
  return __builtin_amdgcn_mfma_f32_16x16x32_bf16(a, b, c, 0, 0, 0);
}

#define GLOAD16(g, s) __builtin_amdgcn_global_load_lds( \
    (__attribute__((address_space(1))) void*)(g), \
    (__attribute__((address_space(3))) void*)(s), 16, 0, 0)

// ------------------------------------------------------- split x (hi only)
__global__ void k_splitx_hi(const float* __restrict__ x, u16* __restrict__ xh) {
  const int n4 = NROWS * ND / 4;
  for (int i = blockIdx.x * blockDim.x + threadIdx.x; i < n4;
       i += gridDim.x * blockDim.x) {
    f32x4 v = ((const f32x4*)x)[i];
    u16x4 hv;
#pragma unroll
    for (int j = 0; j < 4; ++j) hv[j] = bf16rn(v[j]);
    ((u16x4*)xh)[i] = hv;
  }
}

// ------------------------------------------------- transpose weights (bf16)
__global__ void k_prep_w(const float* __restrict__ Wq, const float* __restrict__ Wk,
                         const float* __restrict__ Wv, const float* __restrict__ Wo,
                         u16* __restrict__ wth) {
  int idx = blockIdx.x * 256 + threadIdx.x;
  if (idx >= 3072 * 768) return;
  int j = idx / 768, k = idx % 768;
  int mat = j / 768;                 // 0=Wq 1=Wk 2=Wv 3=Wo
  int jj = j - mat * 768;
  const float* W = (mat == 0) ? Wq : (mat == 1) ? Wk : (mat == 2) ? Wv : Wo;
  wth[idx] = bf16rn(W[k * 768 + jj]);
}

// ---------------------------------------------------------------- QKV GEMM
// C[32768 x 2304] = Xh @ [Wq|Wk|Wv] + bias, epilogue RoPE. Single-bf16.
__global__ __launch_bounds__(256, 3) void k_qkv(
    const u16* __restrict__ xh, const u16* __restrict__ wth,
    const float* __restrict__ bq, const float* __restrict__ bk,
    const float* __restrict__ bv,
    const float* __restrict__ cy, const float* __restrict__ sy,
    const float* __restrict__ cx, const float* __restrict__ sx,
    u16* __restrict__ Qh, u16* __restrict__ Kh, u16* __restrict__ Vth)
{
  __shared__ char lds[32768];  // A 16K | B 16K, 128B rows, XOR-swizzled
  const int t = threadIdx.x, l = t & 63, w = t >> 6;
  const int lr = l & 15, lg = l >> 4;
  const int bid = blockIdx.x;
  const int swz = (bid & 7) * 576 + (bid >> 3);   // 4608 = 8 * 576
  const int n0 = (swz / 18) * 128;
  const int j0 = (swz % 18) * 128;
  const int wr = w >> 1, wc = w & 1;
  f32x4 acc[4][4] = {};

  for (int kt = 0; kt < 12; ++kt) {
    const int k0 = kt * 64;
    __syncthreads();
#pragma unroll
    for (int i = 0; i < 4; ++i) {
      int o = (i * 4 + w) * 1024 + l * 16;   // [0,16384)
      int r = o >> 7;                        // tile row 0..127
      int gb = (o & 127) ^ ((r & 7) << 4);   // inverse-swizzled source byte
      size_t ga = ((size_t)(n0 + r) * 768 + k0) * 2 + gb;
      size_t gw = ((size_t)(j0 + r) * 768 + k0) * 2 + gb;
      GLOAD16((const char*)xh + ga, lds + o);
      GLOAD16((const char*)wth + gw, lds + 16384 + o);
    }
    __syncthreads();
#pragma unroll
    for (int s = 0; s < 2; ++s) {
      s16x8 ah[4], bh_[4];
#pragma unroll
      for (int mi = 0; mi < 4; ++mi) {
        int r = wr * 64 + mi * 16 + lr;
        int off = r * 128 + ((s * 64 + lg * 16) ^ ((r & 7) << 4));
        ah[mi] = *(const s16x8*)(lds + off);
      }
#pragma unroll
      for (int ni = 0; ni < 4; ++ni) {
        int r = wc * 64 + ni * 16 + lr;
        int off = r * 128 + ((s * 64 + lg * 16) ^ ((r & 7) << 4));
        bh_[ni] = *(const s16x8*)(lds + 16384 + off);
      }
#pragma unroll
      for (int mi = 0; mi < 4; ++mi)
#pragma unroll
        for (int ni = 0; ni < 4; ++ni)
          acc[mi][ni] = mfma16(ah[mi], bh_[ni], acc[mi][ni]);
    }
  }

  // epilogue: C row = n0+wr*64+mi*16+lg*4+r, col = j0+wc*64+ni*16+lr
#pragma unroll
  for (int ni = 0; ni < 4; ++ni) {
    const int col = j0 + wc * 64 + ni * 16 + lr;
    const int mat = col / 768;     // uniform per block (768 = 6*128)
    const int cj = col % 768;
    const int h = cj >> 6, d = cj & 63;
    const float bias = (mat == 0 ? bq : mat == 1 ? bk : bv)[cj];
    const float* ct = (d < 32) ? cy : cx;
    const float* st = (d < 32) ? sy : sx;
    const int e = d & 31;
    const bool odd = (d & 1) != 0;
#pragma unroll
    for (int mi = 0; mi < 4; ++mi) {
      const int nbase = n0 + wr * 64 + mi * 16 + lg * 4;
      if (mat == 2) {
        const int b = nbase >> 11, m = nbase & 2047;
        const size_t off = ((size_t)(b * 12 + h) * 64 + d) * 2048 + m;
        u16x4 hv;
#pragma unroll
        for (int r = 0; r < 4; ++r) hv[r] = bf16rn(acc[mi][ni][r] + bias);
        *(u16x4*)(Vth + off) = hv;
      } else {
#pragma unroll
        for (int r = 0; r < 4; ++r) {
          const int n = nbase + r;
          const int b = n >> 11, m = n & 2047;
          float v = acc[mi][ni][r] + bias;
          float p = __shfl_xor(v, 1);     // partner channel (col^1), post-bias
          float c = ct[m * 32 + e], sn = st[m * 32 + e];
          float ov = odd ? (v * c + p * sn) : (v * c - p * sn);
          if (mat == 0) ov *= QSCALE;     // fold softmax scale * log2(e) into Q
          const size_t off = ((size_t)(b * 12 + h) * 2048 + m) * 64 + d;
          (mat == 0 ? Qh : Kh)[off] = bf16rn(ov);
        }
      }
    }
  }
}

// ---------------------------------------------------------- flash attention
// 1D grid 3072, XCD-swizzled. Swapped QK^T; P in registers (cvt_pk+permlane);
// row-sums via ones-MFMA. Main loop UNROLLED x2 so the LDS buffer index is
// compile-time: all 32 ds_read addresses collapse to 2 per-lane registers +
// immediate offsets; staging uses uniform base + per-lane 32b offsets (saddr).
// setprio(1) around MFMA clusters (T5).
__global__ __launch_bounds__(256, 4) void k_attn(
    const u16* __restrict__ Qh, const u16* __restrict__ Kh,
    const u16* __restrict__ Vth, u16* __restrict__ Oh)
{
  __shared__ char lds[32768]; // dbuf: {K 8K | Vt 8K} x 2
  const int t = threadIdx.x, l = t & 63, w = t >> 6;
  const int lr = l & 15, lg = l >> 4;
  const int bid = blockIdx.x;
  const int swz = (bid & 7) * 384 + (bid >> 3);   // 3072 = 8 * 384
  const int bh = swz >> 4;
  const int q0 = (swz & 15) * 128;
  const size_t base = (size_t)bh * (2048 * 64);

  // Q fragments (pre-scaled by SCALE*log2e, roped); serve as MFMA B-operand.
  s16x8 qf[2][2];
#pragma unroll
  for (int mi = 0; mi < 2; ++mi)
#pragma unroll
    for (int ks = 0; ks < 2; ++ks) {
      size_t off = base + (size_t)(q0 + w * 32 + mi * 16 + lr) * 64 + ks * 32 + lg * 8;
      qf[mi][ks] = *(const s16x8*)(Qh + off);
    }

  f32x4 oacc[2][4] = {};
  f32x4 sacc[2] = {};
  const f32x4 fz = {0.f, 0.f, 0.f, 0.f};
  s16x8 ones;
#pragma unroll
  for (int j = 0; j < 8; ++j) ones[j] = (short)0x3F80;   // bf16 1.0

  // staging geometry: uniform bases (SGPR-able) + loop-invariant lane offsets
  const char* kuni = (const char*)Kh + base * 2;
  const char* vuni = (const char*)Vth + base * 2;
  const int lo0 = w * 1024 + l * 16;       // LDS dest offset [0,4096)
  const int lo1 = lo0 + 4096;              // [4096,8192)
  const int r0 = lo0 >> 7, r1 = lo1 >> 7;
  const int gb0 = (lo0 & 127) ^ ((r0 & 7) << 4);
  const int gb1 = (lo1 & 127) ^ ((r1 & 7) << 4);
  const int lk0 = r0 * 128 + gb0,  lk1 = r1 * 128 + gb1;    // K lane offsets
  const int lv0 = r0 * 4096 + gb0, lv1 = r1 * 4096 + gb1;   // Vt lane offsets

  // LDS read bases: swizzle depends only on lr -> 2 regs + immediates
  const int sw = (lr & 7) << 4;
  const int akb0 = lr * 128 + ((lg * 16) ^ sw);
  const int akb1 = lr * 128 + ((64 + lg * 16) ^ sw);

#define STAGE_TO(BN, kc1) do { \
    const size_t ko = (size_t)(kc1) * 8192; \
    const size_t vo = (size_t)(kc1) * 128; \
    GLOAD16(kuni + ko + lk0, lds + (BN) * 16384 + lo0); \
    GLOAD16(kuni + ko + lk1, lds + (BN) * 16384 + lo1); \
    GLOAD16(vuni + vo + lv0, lds + (BN) * 16384 + 8192 + lo0); \
    GLOAD16(vuni + vo + lv1, lds + (BN) * 16384 + 8192 + lo1); \
  } while (0)

  STAGE_TO(0, 0);
  asm volatile("s_waitcnt vmcnt(0)" ::: "memory");
  __syncthreads();

#define BODY(B, kc) do { \
    if ((kc) < 31) STAGE_TO((B) ^ 1, (kc) + 1); \
    const char* kvB = lds + (B) * 16384; \
    f32x4 s[4][2]; \
    { \
      s16x8 kb[4]; \
      _Pragma("unroll") \
      for (int ni = 0; ni < 4; ++ni) \
        kb[ni] = *(const s16x8*)(kvB + akb0 + ni * 2048); \
      __builtin_amdgcn_s_setprio(1); \
      _Pragma("unroll") \
      for (int ni = 0; ni < 4; ++ni) \
        _Pragma("unroll") \
        for (int mi = 0; mi < 2; ++mi) \
          s[ni][mi] = mfma16(kb[ni], qf[mi][0], fz); \
      __builtin_amdgcn_s_setprio(0); \
      _Pragma("unroll") \
      for (int ni = 0; ni < 4; ++ni) \
        kb[ni] = *(const s16x8*)(kvB + akb1 + ni * 2048); \
      __builtin_amdgcn_s_setprio(1); \
      _Pragma("unroll") \
      for (int ni = 0; ni < 4; ++ni) \
        _Pragma("unroll") \
        for (int mi = 0; mi < 2; ++mi) \
          s[ni][mi] = mfma16(kb[ni], qf[mi][1], s[ni][mi]); \
      __builtin_amdgcn_s_setprio(0); \
    } \
    s16x8 paf[2][2]; \
    _Pragma("unroll") \
    for (int mi = 0; mi < 2; ++mi) { \
      uint32_t pk[4][2]; \
      _Pragma("unroll") \
      for (int ni = 0; ni < 4; ++ni) { \
        float p0 = __builtin_amdgcn_exp2f(s[ni][mi][0]); \
        float p1 = __builtin_amdgcn_exp2f(s[ni][mi][1]); \
        float p2 = __builtin_amdgcn_exp2f(s[ni][mi][2]); \
        float p3 = __builtin_amdgcn_exp2f(s[ni][mi][3]); \
        asm("v_cvt_pk_bf16_f32 %0, %1, %2" : "=v"(pk[ni][0]) : "v"(p0), "v"(p1)); \
        asm("v_cvt_pk_bf16_f32 %0, %1, %2" : "=v"(pk[ni][1]) : "v"(p2), "v"(p3)); \
      } \
      _Pragma("unroll") \
      for (int c = 0; c < 2; ++c) { \
        uint32_t x0 = pk[2 * c][0], y0 = pk[2 * c + 1][0]; \
        uint32_t x1 = pk[2 * c][1], y1 = pk[2 * c + 1][1]; \
        asm("v_permlane32_swap_b32 %0, %1" : "+v"(x0), "+v"(y0)); \
        asm("v_permlane32_swap_b32 %0, %1" : "+v"(x1), "+v"(y1)); \
        asm("v_permlane16_swap_b32 %0, %1" : "+v"(x0), "+v"(y0)); \
        asm("v_permlane16_swap_b32 %0, %1" : "+v"(x1), "+v"(y1)); \
        union { uint32_t u[4]; s16x8 v; } fr; \
        fr.u[0] = x0; fr.u[1] = x1; fr.u[2] = y0; fr.u[3] = y1; \
        paf[mi][c] = fr.v; \
      } \
    } \
    _Pragma("unroll") \
    for (int c = 0; c < 2; ++c) { \
      const int akbc = c ? akb1 : akb0; \
      s16x8 vf[4]; \
      _Pragma("unroll") \
      for (int di = 0; di < 4; ++di) \
        vf[di] = *(const s16x8*)(kvB + 8192 + akbc + di * 2048); \
      __builtin_amdgcn_s_setprio(1); \
      _Pragma("unroll") \
      for (int mi = 0; mi < 2; ++mi) { \
        sacc[mi] = mfma16(paf[mi][c], ones, sacc[mi]); \
        _Pragma("unroll") \
        for (int di = 0; di < 4; ++di) \
          oacc[mi][di] = mfma16(paf[mi][c], vf[di], oacc[mi][di]); \
      } \
      __builtin_amdgcn_s_setprio(0); \
    } \
    asm volatile("s_waitcnt vmcnt(0)" ::: "memory"); \
    __syncthreads(); \
  } while (0)

  for (int kc2 = 0; kc2 < 16; ++kc2) {
    BODY(0, 2 * kc2);
    BODY(1, 2 * kc2 + 1);
  }
#undef BODY
#undef STAGE_TO

  // finalize: O / rowsum (lane-local via sacc), store hi bf16, layout [n][768]
  const int bb = bh / 12, hh = bh % 12;
#pragma unroll
  for (int mi = 0; mi < 2; ++mi)
#pragma unroll
    for (int i = 0; i < 4; ++i) {
      float inv = __builtin_amdgcn_rcpf(sacc[mi][i]);
      size_t nrow = (size_t)bb * 2048 + q0 + w * 32 + mi * 16 + lg * 4 + i;
#pragma unroll
      for (int di = 0; di < 4; ++di) {
        float v = oacc[mi][di][i] * inv;
        size_t off = nrow * 768 + hh * 64 + di * 16 + lr;
        Oh[off] = bf16rn(v);
      }
    }
}

// ---------------------------------------------------------------- out GEMM
__global__ __launch_bounds__(256, 3) void k_out(
    const u16* __restrict__ oh, const u16* __restrict__ wth,
    const float* __restrict__ bo, float* __restrict__ out)
{
  __shared__ char lds[32768];
  const int t = threadIdx.x, l = t & 63, w = t >> 6;
  const int lr = l & 15, lg = l >> 4;
  const int bid = blockIdx.x;
  const int swz = (bid & 7) * 192 + (bid >> 3);   // 1536 = 8 * 192
  const int n0 = (swz / 6) * 128;
  const int j0 = (swz % 6) * 128;
  const int wr = w >> 1, wc = w & 1;
  f32x4 acc[4][4] = {};

  for (int kt = 0; kt < 12; ++kt) {
    const int k0 = kt * 64;
    __syncthreads();
#pragma unroll
    for (int i = 0; i < 4; ++i) {
      int o = (i * 4 + w) * 1024 + l * 16;
      int r = o >> 7;
      int gb = (o & 127) ^ ((r & 7) << 4);
      size_t ga = ((size_t)(n0 + r) * 768 + k0) * 2 + gb;
      size_t gw = ((size_t)(2304 + j0 + r) * 768 + k0) * 2 + gb;
      GLOAD16((const char*)oh + ga, lds + o);
      GLOAD16((const char*)wth + gw, lds + 16384 + o);
    }
    __syncthreads();
#pragma unroll
    for (int s = 0; s < 2; ++s) {
      s16x8 ah[4], bh_[4];
#pragma unroll
      for (int mi = 0; mi < 4; ++mi) {
        int r = wr * 64 + mi * 16 + lr;
        int off = r * 128 + ((s * 64 + lg * 16) ^ ((r & 7) << 4));
        ah[mi] = *(const s16x8*)(lds + off);
      }
#pragma unroll
      for (int ni = 0; ni < 4; ++ni) {
        int r = wc * 64 + ni * 16 + lr;
        int off = r * 128 + ((s * 64 + lg * 16) ^ ((r & 7) << 4));
        bh_[ni] = *(const s16x8*)(lds + 16384 + off);
      }
#pragma unroll
      for (int mi = 0; mi < 4; ++mi)
#pragma unroll
        for (int ni = 0; ni < 4; ++ni)
          acc[mi][ni] = mfma16(ah[mi], bh_[ni], acc[mi][ni]);
    }
  }
#pragma unroll
  for (int ni = 0; ni < 4; ++ni) {
    const int col = j0 + wc * 64 + ni * 16 + lr;
    const float bias = bo[col];
#pragma unroll
    for (int mi = 0; mi < 4; ++mi) {
      const int nb = n0 + wr * 64 + mi * 16 + lg * 4;
#pragma unroll
      for (int r = 0; r < 4; ++r)
        out[(size_t)(nb + r) * 768 + col] = acc[mi][ni][r] + bias;
    }
  }
}

// ---------------------------------------------------------------- launcher
extern "C" void kernel_launch(void* const* d_in, const int* in_sizes, int n_in,
                              void* d_out, int out_size, void* d_ws, size_t ws_size,
                              hipStream_t stream) {
  const float* x  = (const float*)d_in[0];
  const float* cy = (const float*)d_in[1];
  const float* sy = (const float*)d_in[2];
  const float* cx = (const float*)d_in[3];
  const float* sx = (const float*)d_in[4];
  const float* Wq = (const float*)d_in[5];
  const float* bq = (const float*)d_in[6];
  const float* Wk = (const float*)d_in[7];
  const float* bk = (const float*)d_in[8];
  const float* Wv = (const float*)d_in[9];
  const float* bv = (const float*)d_in[10];
  const float* Wo = (const float*)d_in[11];
  const float* bo = (const float*)d_in[12];
  float* out = (float*)d_out;

  // Workspace (~105 MB): Xh | Wth | Vth.  O aliases Xh (X dead after k_qkv).
  char* ws = (char*)d_ws;
  size_t o = 0;
  const size_t SZ_X = (size_t)NROWS * ND * 2;        // 50331648 B
  const size_t SZ_W = (size_t)3072 * 768 * 2;        // 4718592 B
  u16* Xh  = (u16*)(ws + o); o += SZ_X;
  u16* Wth = (u16*)(ws + o); o += SZ_W;
  u16* Vth = (u16*)(ws + o); o += SZ_X;
  u16* Oh  = Xh;

  // Q and K live in d_out (exactly 2 x 50331648 B = out buffer); dead
  // before k_out overwrites d_out with the final result.
  u16* Qh = (u16*)d_out;
  u16* Kh = Qh + (size_t)NROWS * 768;

  k_splitx_hi<<<2048, 256, 0, stream>>>(x, Xh);
  k_prep_w<<<(3072 * 768 + 255) / 256, 256, 0, stream>>>(Wq, Wk, Wv, Wo, Wth);
  k_qkv<<<4608, 256, 0, stream>>>(Xh, Wth, bq, bk, bv,
                                  cy, sy, cx, sx, Qh, Kh, Vth);
  k_attn<<<3072, 256, 0, stream>>>(Qh, Kh, Vth, Oh);
  k_out<<<1536, 256, 0, stream>>>(Oh, Wth, bo, out);
}

// Round 10
// 437.434 us; speedup vs baseline: 1.0587x; 1.0587x over previous
//
#include <hip/hip_runtime.h>
#include <hip/hip_bf16.h>
#include <stdint.h>

typedef __attribute__((ext_vector_type(4))) float f32x4;
typedef __attribute__((ext_vector_type(8))) short s16x8;
typedef __attribute__((ext_vector_type(4))) unsigned short u16x4;
typedef unsigned short u16;

#define NB 16
#define NM 2048
#define ND 768
#define NH 12
#define NROWS (NB*NM)
// 0.125 * log2(e)
#define QSCALE 0.18033688011112042f

__device__ __forceinline__ u16 bf16rn(float v) {
  union { float f; uint32_t u; } x; x.f = v;
  uint32_t r = x.u + 0x7FFFu + ((x.u >> 16) & 1u);
  return (u16)(r >> 16);
}

__device__ __forceinline__ f32x4 mfma16(s16x8 a, s16x8 b, f32x4 c) {
  return __builtin_amdgcn_mfma_f32_16x16x32_bf16(a, b, c, 0, 0, 0);
}

#define GLOAD16(g, s) __builtin_amdgcn_global_load_lds( \
    (__attribute__((address_space(1))) void*)(g), \
    (__attribute__((address_space(3))) void*)(s), 16, 0, 0)

// --------------------------- merged prep: split x (hi) + transpose weights
// blocks [0,2048): x -> bf16-hi, grid-stride. blocks [2048,11264): Wt[j][k]=W[k][j]
__global__ void k_prep(const float* __restrict__ x, u16* __restrict__ xh,
                       const float* __restrict__ Wq, const float* __restrict__ Wk,
                       const float* __restrict__ Wv, const float* __restrict__ Wo,
                       u16* __restrict__ wth) {
  const int bid = blockIdx.x;
  if (bid < 2048) {
    const int n4 = NROWS * ND / 4;
    for (int i = bid * 256 + threadIdx.x; i < n4; i += 2048 * 256) {
      f32x4 v = ((const f32x4*)x)[i];
      u16x4 hv;
#pragma unroll
      for (int j = 0; j < 4; ++j) hv[j] = bf16rn(v[j]);
      ((u16x4*)xh)[i] = hv;
    }
  } else {
    int idx = (bid - 2048) * 256 + threadIdx.x;
    if (idx >= 3072 * 768) return;
    int j = idx / 768, k = idx % 768;
    int mat = j / 768;                 // 0=Wq 1=Wk 2=Wv 3=Wo
    int jj = j - mat * 768;
    const float* W = (mat == 0) ? Wq : (mat == 1) ? Wk : (mat == 2) ? Wv : Wo;
    wth[idx] = bf16rn(W[k * 768 + jj]);
  }
}

// ---------------------------------------------------------------- QKV GEMM
// C[32768 x 2304] = Xh @ [Wq|Wk|Wv] + bias, epilogue RoPE. Single-bf16.
// Incremental staging pointers (+128 B per K-step).
__global__ __launch_bounds__(256, 3) void k_qkv(
    const u16* __restrict__ xh, const u16* __restrict__ wth,
    const float* __restrict__ bq, const float* __restrict__ bk,
    const float* __restrict__ bv,
    const float* __restrict__ cy, const float* __restrict__ sy,
    const float* __restrict__ cx, const float* __restrict__ sx,
    u16* __restrict__ Qh, u16* __restrict__ Kh, u16* __restrict__ Vth)
{
  __shared__ char lds[32768];  // A 16K | B 16K, 128B rows, XOR-swizzled
  const int t = threadIdx.x, l = t & 63, w = t >> 6;
  const int lr = l & 15, lg = l >> 4;
  const int bid = blockIdx.x;
  const int swz = (bid & 7) * 576 + (bid >> 3);   // 4608 = 8 * 576
  const int n0 = (swz / 18) * 128;
  const int j0 = (swz % 18) * 128;
  const int wr = w >> 1, wc = w & 1;
  f32x4 acc[4][4] = {};

  // staging pointers (advance +128 B per K-step; k0 starts at 0)
  const char* pa[4];
  const char* pb[4];
  int lofs[4];
#pragma unroll
  for (int i = 0; i < 4; ++i) {
    int o = (i * 4 + w) * 1024 + l * 16;   // [0,16384)
    int r = o >> 7;                        // tile row 0..127
    int gb = (o & 127) ^ ((r & 7) << 4);   // inverse-swizzled source byte
    lofs[i] = o;
    pa[i] = (const char*)xh + (size_t)(n0 + r) * 1536 + gb;
    pb[i] = (const char*)wth + (size_t)(j0 + r) * 1536 + gb;
  }

  for (int kt = 0; kt < 12; ++kt) {
    __syncthreads();
#pragma unroll
    for (int i = 0; i < 4; ++i) {
      GLOAD16(pa[i], lds + lofs[i]);
      GLOAD16(pb[i], lds + 16384 + lofs[i]);
      pa[i] += 128; pb[i] += 128;
    }
    __syncthreads();
#pragma unroll
    for (int s = 0; s < 2; ++s) {
      s16x8 ah[4], bh_[4];
#pragma unroll
      for (int mi = 0; mi < 4; ++mi) {
        int r = wr * 64 + mi * 16 + lr;
        int off = r * 128 + ((s * 64 + lg * 16) ^ ((r & 7) << 4));
        ah[mi] = *(const s16x8*)(lds + off);
      }
#pragma unroll
      for (int ni = 0; ni < 4; ++ni) {
        int r = wc * 64 + ni * 16 + lr;
        int off = r * 128 + ((s * 64 + lg * 16) ^ ((r & 7) << 4));
        bh_[ni] = *(const s16x8*)(lds + 16384 + off);
      }
#pragma unroll
      for (int mi = 0; mi < 4; ++mi)
#pragma unroll
        for (int ni = 0; ni < 4; ++ni)
          acc[mi][ni] = mfma16(ah[mi], bh_[ni], acc[mi][ni]);
    }
  }

  // epilogue: C row = n0+wr*64+mi*16+lg*4+r, col = j0+wc*64+ni*16+lr
#pragma unroll
  for (int ni = 0; ni < 4; ++ni) {
    const int col = j0 + wc * 64 + ni * 16 + lr;
    const int mat = col / 768;     // uniform per block (768 = 6*128)
    const int cj = col % 768;
    const int h = cj >> 6, d = cj & 63;
    const float bias = (mat == 0 ? bq : mat == 1 ? bk : bv)[cj];
    const float* ct = (d < 32) ? cy : cx;
    const float* st = (d < 32) ? sy : sx;
    const int e = d & 31;
    const bool odd = (d & 1) != 0;
#pragma unroll
    for (int mi = 0; mi < 4; ++mi) {
      const int nbase = n0 + wr * 64 + mi * 16 + lg * 4;
      if (mat == 2) {
        const int b = nbase >> 11, m = nbase & 2047;
        const size_t off = ((size_t)(b * 12 + h) * 64 + d) * 2048 + m;
        u16x4 hv;
#pragma unroll
        for (int r = 0; r < 4; ++r) hv[r] = bf16rn(acc[mi][ni][r] + bias);
        *(u16x4*)(Vth + off) = hv;
      } else {
#pragma unroll
        for (int r = 0; r < 4; ++r) {
          const int n = nbase + r;
          const int b = n >> 11, m = n & 2047;
          float v = acc[mi][ni][r] + bias;
          float p = __shfl_xor(v, 1);     // partner channel (col^1), post-bias
          float c = ct[m * 32 + e], sn = st[m * 32 + e];
          float ov = odd ? (v * c + p * sn) : (v * c - p * sn);
          if (mat == 0) ov *= QSCALE;     // fold softmax scale * log2(e) into Q
          const size_t off = ((size_t)(b * 12 + h) * 2048 + m) * 64 + d;
          (mat == 0 ? Qh : Kh)[off] = bf16rn(ov);
        }
      }
    }
  }
}

// ---------------------------------------------------------- flash attention
// (R8 version — best measured: 200 us, 0 bank conflicts.)
// 1D grid 3072, XCD-swizzled. Swapped QK^T; P in registers via cvt_pk +
// permlane swaps. Row-sums via ones-MFMA. Incremental staging pointers.
__global__ __launch_bounds__(256, 4) void k_attn(
    const u16* __restrict__ Qh, const u16* __restrict__ Kh,
    const u16* __restrict__ Vth, u16* __restrict__ Oh)
{
  __shared__ char lds[32768]; // dbuf: {K 8K | Vt 8K} x 2
  const int t = threadIdx.x, l = t & 63, w = t >> 6;
  const int lr = l & 15, lg = l >> 4;
  const int bid = blockIdx.x;
  const int swz = (bid & 7) * 384 + (bid >> 3);   // 3072 = 8 * 384
  const int bh = swz >> 4;
  const int q0 = (swz & 15) * 128;
  const size_t base = (size_t)bh * (2048 * 64);

  // Q fragments (pre-scaled by SCALE*log2e, roped); serve as MFMA B-operand.
  s16x8 qf[2][2];
#pragma unroll
  for (int mi = 0; mi < 2; ++mi)
#pragma unroll
    for (int ks = 0; ks < 2; ++ks) {
      size_t off = base + (size_t)(q0 + w * 32 + mi * 16 + lr) * 64 + ks * 32 + lg * 8;
      qf[mi][ks] = *(const s16x8*)(Qh + off);
    }

  f32x4 oacc[2][4] = {};
  f32x4 sacc[2] = {};
  const f32x4 fz = {0.f, 0.f, 0.f, 0.f};
  s16x8 ones;
#pragma unroll
  for (int j = 0; j < 8; ++j) ones[j] = (short)0x3F80;   // bf16 1.0

  // per-lane staging state (advanced incrementally each chunk)
  int lo0, lo1;
  const char *ka0, *ka1, *va0, *va1;
  {
    int o0 = w * 1024 + l * 16;          // [0,4096)
    int o1 = o0 + 4096;                  // [4096,8192)
    int r0 = o0 >> 7, r1 = o1 >> 7;
    int gb0 = (o0 & 127) ^ ((r0 & 7) << 4);
    int gb1 = (o1 & 127) ^ ((r1 & 7) << 4);
    lo0 = o0; lo1 = o1;
    ka0 = (const char*)Kh + (base + (size_t)r0 * 64) * 2 + gb0;
    ka1 = (const char*)Kh + (base + (size_t)r1 * 64) * 2 + gb1;
    va0 = (const char*)Vth + (base + (size_t)r0 * 2048) * 2 + gb0;
    va1 = (const char*)Vth + (base + (size_t)r1 * 2048) * 2 + gb1;
  }
  auto STAGE = [&](int b) {
    char* dst = lds + b * 16384;
    GLOAD16(ka0, dst + lo0);
    GLOAD16(ka1, dst + lo1);
    GLOAD16(va0, dst + 8192 + lo0);
    GLOAD16(va1, dst + 8192 + lo1);
    ka0 += 8192; ka1 += 8192;            // next chunk: +64 keys * 128 B
    va0 += 128;  va1 += 128;             // next chunk: +64 cols * 2 B
  };

  STAGE(0);
  asm volatile("s_waitcnt vmcnt(0)" ::: "memory");
  __syncthreads();

  for (int kc = 0; kc < 32; ++kc) {
    const int cur = kc & 1;
    if (kc < 31) STAGE(cur ^ 1);         // async loads overlap compute
    const char* kv = lds + cur * 16384;

    // S^T = K Q^T : s[ni][mi], lane holds key = ni*16+lg*4+i, q = mi*16+lr
    f32x4 s[4][2];
    {
      s16x8 kb[4];
#pragma unroll
      for (int ni = 0; ni < 4; ++ni) {
        int r = ni * 16 + lr;
        kb[ni] = *(const s16x8*)(kv + r * 128 + ((lg * 16) ^ ((r & 7) << 4)));
      }
#pragma unroll
      for (int ni = 0; ni < 4; ++ni)
#pragma unroll
        for (int mi = 0; mi < 2; ++mi)
          s[ni][mi] = mfma16(kb[ni], qf[mi][0], fz);      // ks=0: C = 0
#pragma unroll
      for (int ni = 0; ni < 4; ++ni) {
        int r = ni * 16 + lr;
        kb[ni] = *(const s16x8*)(kv + r * 128 + ((64 + lg * 16) ^ ((r & 7) << 4)));
      }
#pragma unroll
      for (int ni = 0; ni < 4; ++ni)
#pragma unroll
        for (int mi = 0; mi < 2; ++mi)
          s[ni][mi] = mfma16(kb[ni], qf[mi][1], s[ni][mi]); // ks=1: accumulate
    }

    // p = exp2(s); cvt_pk to bf16 pairs; permlane-redistribute into PV A-frags
    s16x8 paf[2][2];   // [mi][c]
#pragma unroll
    for (int mi = 0; mi < 2; ++mi) {
      uint32_t pk[4][2];
#pragma unroll
      for (int ni = 0; ni < 4; ++ni) {
        float p0 = __builtin_amdgcn_exp2f(s[ni][mi][0]);
        float p1 = __builtin_amdgcn_exp2f(s[ni][mi][1]);
        float p2 = __builtin_amdgcn_exp2f(s[ni][mi][2]);
        float p3 = __builtin_amdgcn_exp2f(s[ni][mi][3]);
        asm("v_cvt_pk_bf16_f32 %0, %1, %2" : "=v"(pk[ni][0]) : "v"(p0), "v"(p1));
        asm("v_cvt_pk_bf16_f32 %0, %1, %2" : "=v"(pk[ni][1]) : "v"(p2), "v"(p3));
      }
#pragma unroll
      for (int c = 0; c < 2; ++c) {
        uint32_t x0 = pk[2 * c][0], y0 = pk[2 * c + 1][0];
        uint32_t x1 = pk[2 * c][1], y1 = pk[2 * c + 1][1];
        // step A: swap ni-bit <-> lane bit5
        asm("v_permlane32_swap_b32 %0, %1" : "+v"(x0), "+v"(y0));
        asm("v_permlane32_swap_b32 %0, %1" : "+v"(x1), "+v"(y1));
        // step B: swap M-bit <-> lane bit4
        asm("v_permlane16_swap_b32 %0, %1" : "+v"(x0), "+v"(y0));
        asm("v_permlane16_swap_b32 %0, %1" : "+v"(x1), "+v"(y1));
        union { uint32_t u[4]; s16x8 v; } fr;
        fr.u[0] = x0; fr.u[1] = x1; fr.u[2] = y0; fr.u[3] = y1;
        paf[mi][c] = fr.v;
      }
    }

    // O += P @ V ; row-sums += P @ ones (denominator on the MFMA pipe)
#pragma unroll
    for (int c = 0; c < 2; ++c) {
      s16x8 vf[4];
#pragma unroll
      for (int di = 0; di < 4; ++di) {
        int r = di * 16 + lr;
        int off = r * 128 + ((c * 64 + lg * 16) ^ ((r & 7) << 4));
        vf[di] = *(const s16x8*)(kv + 8192 + off);
      }
#pragma unroll
      for (int mi = 0; mi < 2; ++mi) {
        sacc[mi] = mfma16(paf[mi][c], ones, sacc[mi]);
#pragma unroll
        for (int di = 0; di < 4; ++di)
          oacc[mi][di] = mfma16(paf[mi][c], vf[di], oacc[mi][di]);
      }
    }

    // my prefetch landed; all waves done reading buf[cur]
    asm volatile("s_waitcnt vmcnt(0)" ::: "memory");
    __syncthreads();
  }

  // finalize: O / rowsum (lane-local via sacc), store hi bf16, layout [n][768]
  const int bb = bh / 12, hh = bh % 12;
#pragma unroll
  for (int mi = 0; mi < 2; ++mi)
#pragma unroll
    for (int i = 0; i < 4; ++i) {
      float inv = __builtin_amdgcn_rcpf(sacc[mi][i]);
      size_t nrow = (size_t)bb * 2048 + q0 + w * 32 + mi * 16 + lg * 4 + i;
#pragma unroll
      for (int di = 0; di < 4; ++di) {
        float v = oacc[mi][di][i] * inv;
        size_t off = nrow * 768 + hh * 64 + di * 16 + lr;
        Oh[off] = bf16rn(v);
      }
    }
}

// ---------------------------------------------------------------- out GEMM
__global__ __launch_bounds__(256, 3) void k_out(
    const u16* __restrict__ oh, const u16* __restrict__ wth,
    const float* __restrict__ bo, float* __restrict__ out)
{
  __shared__ char lds[32768];
  const int t = threadIdx.x, l = t & 63, w = t >> 6;
  const int lr = l & 15, lg = l >> 4;
  const int bid = blockIdx.x;
  const int swz = (bid & 7) * 192 + (bid >> 3);   // 1536 = 8 * 192
  const int n0 = (swz / 6) * 128;
  const int j0 = (swz % 6) * 128;
  const int wr = w >> 1, wc = w & 1;
  f32x4 acc[4][4] = {};

  const char* pa[4];
  const char* pb[4];
  int lofs[4];
#pragma unroll
  for (int i = 0; i < 4; ++i) {
    int o = (i * 4 + w) * 1024 + l * 16;
    int r = o >> 7;
    int gb = (o & 127) ^ ((r & 7) << 4);
    lofs[i] = o;
    pa[i] = (const char*)oh + (size_t)(n0 + r) * 1536 + gb;
    pb[i] = (const char*)wth + (size_t)(2304 + j0 + r) * 1536 + gb;
  }

  for (int kt = 0; kt < 12; ++kt) {
    __syncthreads();
#pragma unroll
    for (int i = 0; i < 4; ++i) {
      GLOAD16(pa[i], lds + lofs[i]);
      GLOAD16(pb[i], lds + 16384 + lofs[i]);
      pa[i] += 128; pb[i] += 128;
    }
    __syncthreads();
#pragma unroll
    for (int s = 0; s < 2; ++s) {
      s16x8 ah[4], bh_[4];
#pragma unroll
      for (int mi = 0; mi < 4; ++mi) {
        int r = wr * 64 + mi * 16 + lr;
        int off = r * 128 + ((s * 64 + lg * 16) ^ ((r & 7) << 4));
        ah[mi] = *(const s16x8*)(lds + off);
      }
#pragma unroll
      for (int ni = 0; ni < 4; ++ni) {
        int r = wc * 64 + ni * 16 + lr;
        int off = r * 128 + ((s * 64 + lg * 16) ^ ((r & 7) << 4));
        bh_[ni] = *(const s16x8*)(lds + 16384 + off);
      }
#pragma unroll
      for (int mi = 0; mi < 4; ++mi)
#pragma unroll
        for (int ni = 0; ni < 4; ++ni)
          acc[mi][ni] = mfma16(ah[mi], bh_[ni], acc[mi][ni]);
    }
  }
#pragma unroll
  for (int ni = 0; ni < 4; ++ni) {
    const int col = j0 + wc * 64 + ni * 16 + lr;
    const float bias = bo[col];
#pragma unroll
    for (int mi = 0; mi < 4; ++mi) {
      const int nb = n0 + wr * 64 + mi * 16 + lg * 4;
#pragma unroll
      for (int r = 0; r < 4; ++r)
        out[(size_t)(nb + r) * 768 + col] = acc[mi][ni][r] + bias;
    }
  }
}

// ---------------------------------------------------------------- launcher
extern "C" void kernel_launch(void* const* d_in, const int* in_sizes, int n_in,
                              void* d_out, int out_size, void* d_ws, size_t ws_size,
                              hipStream_t stream) {
  const float* x  = (const float*)d_in[0];
  const float* cy = (const float*)d_in[1];
  const float* sy = (const float*)d_in[2];
  const float* cx = (const float*)d_in[3];
  const float* sx = (const float*)d_in[4];
  const float* Wq = (const float*)d_in[5];
  const float* bq = (const float*)d_in[6];
  const float* Wk = (const float*)d_in[7];
  const float* bk = (const float*)d_in[8];
  const float* Wv = (const float*)d_in[9];
  const float* bv = (const float*)d_in[10];
  const float* Wo = (const float*)d_in[11];
  const float* bo = (const float*)d_in[12];
  float* out = (float*)d_out;

  // Workspace (~105 MB): Xh | Wth | Vth.  O aliases Xh (X dead after k_qkv).
  char* ws = (char*)d_ws;
  size_t o = 0;
  const size_t SZ_X = (size_t)NROWS * ND * 2;        // 50331648 B
  const size_t SZ_W = (size_t)3072 * 768 * 2;        // 4718592 B
  u16* Xh  = (u16*)(ws + o); o += SZ_X;
  u16* Wth = (u16*)(ws + o); o += SZ_W;
  u16* Vth = (u16*)(ws + o); o += SZ_X;
  u16* Oh  = Xh;

  // Q and K live in d_out (exactly 2 x 50331648 B = out buffer); dead
  // before k_out overwrites d_out with the final result.
  u16* Qh = (u16*)d_out;
  u16* Kh = Qh + (size_t)NROWS * 768;

  k_prep<<<11264, 256, 0, stream>>>(x, Xh, Wq, Wk, Wv, Wo, Wth);
  k_qkv<<<4608, 256, 0, stream>>>(Xh, Wth, bq, bk, bv,
                                  cy, sy, cx, sx, Qh, Kh, Vth);
  k_attn<<<3072, 256, 0, stream>>>(Qh, Kh, Vth, Oh);
  k_out<<<1536, 256, 0, stream>>>(Oh, Wth, bo, out);
}